// Round 1
// baseline (640.999 us; speedup 1.0000x reference)
//
#include <hip/hip_runtime.h>

#define BB 2
#define LL 4096
#define DIMM 512
#define HHH 4
#define DHH 128
#define CCC 64
#define NNN 64
#define BHH 8
#define TOK (BB*LL)      // 8192
#define ROWS (BHH*LL)    // 32768
#define NCH (BHH*NNN)    // 512
#define MAX_LR_C 0.01f
#define EPS_C 1e-6f

__device__ __forceinline__ float sigmoidf_(float x){ return 1.0f/(1.0f + __expf(-x)); }
__device__ __forceinline__ float siluf_(float x){ return x * (1.0f/(1.0f + __expf(-x))); }

// ---------------------------------------------------------------------------
// K1: per-token rmsnorm (store & retrieve), adaptive_lr, gate. One wave/token.
// rc is stored PRE-SHIFTED: rc[b, t-63] = rmsnorm(seq[b,t])*retrieve_scale,
// rows [L-63, L) zeroed. gate likewise shifted (tail rows = sigmoid(0)=0.5).
// ---------------------------------------------------------------------------
__global__ __launch_bounds__(256) void k_rmsnorm(
    const float* __restrict__ seq, const float* __restrict__ sscale,
    const float* __restrict__ rscale, const float* __restrict__ w_ada,
    const float* __restrict__ w_gate, float* __restrict__ s,
    float* __restrict__ rc, float* __restrict__ lr, float* __restrict__ gate)
{
    int tok = blockIdx.x*4 + (threadIdx.x>>6);
    int lane = threadIdx.x & 63;
    int b = tok >> 12;
    int t = tok & 4095;
    const float* x = seq + (size_t)tok*DIMM;
    float v[8]; float ss = 0.f;
    #pragma unroll
    for (int j=0;j<8;j++){ v[j] = x[lane + 64*j]; ss += v[j]*v[j]; }
    #pragma unroll
    for (int m=1;m<64;m<<=1) ss += __shfl_xor(ss, m, 64);
    float rstd = rsqrtf(ss * (1.0f/DIMM) + EPS_C);
    float sv[8], rv[8];
    float pa[4] = {0,0,0,0}, pg[4] = {0,0,0,0};
    #pragma unroll
    for (int j=0;j<8;j++){
        int d = lane + 64*j;
        float nv = v[j]*rstd;
        sv[j] = nv * sscale[d];
        rv[j] = nv * rscale[d];
        #pragma unroll
        for (int h=0;h<4;h++){
            pa[h] += sv[j]*w_ada[d*4+h];
            pg[h] += rv[j]*w_gate[d*4+h];
        }
    }
    float* srow = s + (size_t)tok*DIMM;
    #pragma unroll
    for (int j=0;j<8;j++) srow[lane+64*j] = sv[j];
    if (t >= 63){
        float* rrow = rc + ((size_t)b*LL + (t-63))*DIMM;
        #pragma unroll
        for (int j=0;j<8;j++) rrow[lane+64*j] = rv[j];
    } else {
        float* rrow = rc + ((size_t)b*LL + (LL-63+t))*DIMM;
        #pragma unroll
        for (int j=0;j<8;j++) rrow[lane+64*j] = 0.0f;
    }
    #pragma unroll
    for (int h=0;h<4;h++){
        #pragma unroll
        for (int m=1;m<64;m<<=1){
            pa[h] += __shfl_xor(pa[h], m, 64);
            pg[h] += __shfl_xor(pg[h], m, 64);
        }
    }
    if (lane < 4){
        int h = lane;
        lr[((size_t)(b*4+h))*LL + t] = sigmoidf_(pa[h]) * MAX_LR_C;
        if (t >= 63) gate[((size_t)b*LL + (t-63))*4 + h] = sigmoidf_(pg[h]);
        else         gate[((size_t)b*LL + (LL-63+t))*4 + h] = 0.5f;
    }
}

// ---------------------------------------------------------------------------
// K2: chunk means of s -> ada_mom / decay sigmoids. One block per (b,n).
// ---------------------------------------------------------------------------
__global__ __launch_bounds__(256) void k_chunkstats(
    const float* __restrict__ s, const float* __restrict__ w_mom,
    const float* __restrict__ w_dec, float* __restrict__ ada_mom,
    float* __restrict__ decay)
{
    int b = blockIdx.x >> 6;
    int n = blockIdx.x & 63;
    float pm[4] = {0,0,0,0}, pd[4] = {0,0,0,0};
    #pragma unroll
    for (int rep=0; rep<2; rep++){
        int d = threadIdx.x + rep*256;
        const float* base = s + ((size_t)b*LL + n*64)*DIMM + d;
        float acc = 0.f;
        for (int c=0;c<64;c++) acc += base[(size_t)c*DIMM];
        float mean = acc * (1.0f/64.0f);
        #pragma unroll
        for (int h=0;h<4;h++){ pm[h] += mean*w_mom[d*4+h]; pd[h] += mean*w_dec[d*4+h]; }
    }
    #pragma unroll
    for (int h=0;h<4;h++){
        #pragma unroll
        for (int m=1;m<64;m<<=1){ pm[h]+=__shfl_xor(pm[h],m,64); pd[h]+=__shfl_xor(pd[h],m,64); }
    }
    __shared__ float lds[4][8];
    int wave = threadIdx.x>>6, lane = threadIdx.x&63;
    if (lane==0){
        #pragma unroll
        for (int h=0;h<4;h++){ lds[wave][h]=pm[h]; lds[wave][4+h]=pd[h]; }
    }
    __syncthreads();
    if (threadIdx.x < 8){
        float tot = lds[0][threadIdx.x]+lds[1][threadIdx.x]+lds[2][threadIdx.x]+lds[3][threadIdx.x];
        int h = threadIdx.x & 3;
        int bh = b*4 + h;
        if (threadIdx.x < 4) ada_mom[bh*64+n] = sigmoidf_(tot);
        else                 decay[bh*64+n]   = sigmoidf_(tot);
    }
}

// ---------------------------------------------------------------------------
// Generic fp32 GEMM: 128x128 block tile, BK=16, 256 threads, 8x8 per thread.
// modeA: 0 plain, 1 silu on load.  modeB: 0 row-major KxN, 1 transposed (NxK src).
// modeE: 0 plain C1[row*N+col]
//        1 kv split -> keys C1 / vals C2, head-major
//        2 dP: C1 in-place, C1 = (2/128)*lr[row]*(acc - C1_old)
//        3 dH: C1 in-place, C1 = acc * silu'(C1_old)
//        4 combine: write d_out with +63 token shift, skip rows t >= L-63
//        5 q head split -> C1 head-major
// ---------------------------------------------------------------------------
__global__ __launch_bounds__(256) void k_gemm(
    const float* __restrict__ A, const float* __restrict__ Bm,
    float* __restrict__ C1, float* __restrict__ C2, const float* __restrict__ aux0,
    int M, int N, int K, int modeA, int modeB, int modeE)
{
    __shared__ float As[16][132];
    __shared__ float Bs[16][132];
    int tid = threadIdx.x;
    int row0 = blockIdx.y * 128;
    int col0 = blockIdx.x * 128;
    int m0 = (tid>>4)<<3;
    int n0 = (tid&15)<<3;
    float acc[8][8];
    #pragma unroll
    for (int i=0;i<8;i++)
        #pragma unroll
        for (int j=0;j<8;j++) acc[i][j] = 0.f;
    int lar = tid>>1;           // A row 0..127
    int lak = (tid&1)<<3;       // k-offset 0/8
    int lbk = tid>>4;           // B k-row 0..15
    int lbn = (tid&15)<<3;      // B col group
    for (int k0=0;k0<K;k0+=16){
        float4 a0 = *(const float4*)(A + (size_t)(row0+lar)*(size_t)K + k0+lak);
        float4 a1 = *(const float4*)(A + (size_t)(row0+lar)*(size_t)K + k0+lak+4);
        if (modeA==1){
            a0.x=siluf_(a0.x); a0.y=siluf_(a0.y); a0.z=siluf_(a0.z); a0.w=siluf_(a0.w);
            a1.x=siluf_(a1.x); a1.y=siluf_(a1.y); a1.z=siluf_(a1.z); a1.w=siluf_(a1.w);
        }
        As[lak+0][lar]=a0.x; As[lak+1][lar]=a0.y; As[lak+2][lar]=a0.z; As[lak+3][lar]=a0.w;
        As[lak+4][lar]=a1.x; As[lak+5][lar]=a1.y; As[lak+6][lar]=a1.z; As[lak+7][lar]=a1.w;
        if (modeB==0){
            float4 b0 = *(const float4*)(Bm + (size_t)(k0+lbk)*(size_t)N + col0+lbn);
            float4 b1 = *(const float4*)(Bm + (size_t)(k0+lbk)*(size_t)N + col0+lbn+4);
            *(float4*)&Bs[lbk][lbn]   = b0;
            *(float4*)&Bs[lbk][lbn+4] = b1;
        } else {
            #pragma unroll
            for (int i=0;i<8;i++)
                Bs[lbk][lbn+i] = Bm[(size_t)(col0+lbn+i)*(size_t)K + k0+lbk];
        }
        __syncthreads();
        #pragma unroll
        for (int k=0;k<16;k++){
            float av[8], bv[8];
            *(float4*)&av[0] = *(const float4*)&As[k][m0];
            *(float4*)&av[4] = *(const float4*)&As[k][m0+4];
            *(float4*)&bv[0] = *(const float4*)&Bs[k][n0];
            *(float4*)&bv[4] = *(const float4*)&Bs[k][n0+4];
            #pragma unroll
            for (int i=0;i<8;i++)
                #pragma unroll
                for (int j=0;j<8;j++)
                    acc[i][j] += av[i]*bv[j];
        }
        __syncthreads();
    }
    #pragma unroll
    for (int i=0;i<8;i++){
        int row = row0 + m0 + i;
        #pragma unroll
        for (int j=0;j<8;j++){
            int col = col0 + n0 + j;
            float vacc = acc[i][j];
            if (modeE==0){
                C1[(size_t)row*(size_t)N + col] = vacc;
            } else if (modeE==1){
                int b = row>>12, l = row&4095;
                if (col < 512){
                    int h = col>>7, d = col&127;
                    C1[(((size_t)(b*4+h))*LL + l)*128 + d] = vacc;
                } else {
                    int c2 = col-512; int h = c2>>7, d = c2&127;
                    C2[(((size_t)(b*4+h))*LL + l)*128 + d] = vacc;
                }
            } else if (modeE==2){
                size_t idx = (size_t)row*(size_t)N + col;
                float vv = C1[idx];
                C1[idx] = 0.015625f * aux0[row] * (vacc - vv);
            } else if (modeE==3){
                size_t idx = (size_t)row*(size_t)N + col;
                float hh = C1[idx];
                float sg = sigmoidf_(hh);
                C1[idx] = vacc * sg * (1.f + hh*(1.f - sg));
            } else if (modeE==4){
                int b = row>>12, t = row&4095;
                if (t < LL-63)
                    C1[(((size_t)b*LL) + t + 63)*DIMM + col] = vacc;
            } else { // 5
                int b = row>>12, l = row&4095;
                int h = col>>7, d = col&127;
                C1[(((size_t)(b*4+h))*LL + l)*128 + d] = vacc;
            }
        }
    }
}

// ---------------------------------------------------------------------------
// Batched per-chunk outer product: G[chunk] = A_chunk^T @ B_chunk  (128x128, K=64)
// A,B: ROWS x 128 with chunk rows contiguous (row = chunk*64 + t).
// siluA applies silu to A on load.
// ---------------------------------------------------------------------------
__global__ __launch_bounds__(256) void k_chunk_grad(
    const float* __restrict__ A, const float* __restrict__ Bm,
    float* __restrict__ G, int siluA)
{
    int chunk = blockIdx.x;
    __shared__ float As[16][132];
    __shared__ float Bs[16][132];
    int tid = threadIdx.x;
    int m0 = (tid>>4)<<3;
    int n0 = (tid&15)<<3;
    float acc[8][8];
    #pragma unroll
    for (int i=0;i<8;i++)
        #pragma unroll
        for (int j=0;j<8;j++) acc[i][j] = 0.f;
    int lr_ = tid>>4;
    int lc  = (tid&15)<<3;
    const float* Abase = A + (size_t)chunk*64*128;
    const float* Bbase = Bm + (size_t)chunk*64*128;
    for (int t0=0;t0<64;t0+=16){
        float4 a0 = *(const float4*)(Abase + (size_t)(t0+lr_)*128 + lc);
        float4 a1 = *(const float4*)(Abase + (size_t)(t0+lr_)*128 + lc + 4);
        if (siluA){
            a0.x=siluf_(a0.x); a0.y=siluf_(a0.y); a0.z=siluf_(a0.z); a0.w=siluf_(a0.w);
            a1.x=siluf_(a1.x); a1.y=siluf_(a1.y); a1.z=siluf_(a1.z); a1.w=siluf_(a1.w);
        }
        *(float4*)&As[lr_][lc]   = a0;
        *(float4*)&As[lr_][lc+4] = a1;
        float4 b0 = *(const float4*)(Bbase + (size_t)(t0+lr_)*128 + lc);
        float4 b1 = *(const float4*)(Bbase + (size_t)(t0+lr_)*128 + lc + 4);
        *(float4*)&Bs[lr_][lc]   = b0;
        *(float4*)&Bs[lr_][lc+4] = b1;
        __syncthreads();
        #pragma unroll
        for (int k=0;k<16;k++){
            float av[8], bv[8];
            *(float4*)&av[0] = *(const float4*)&As[k][m0];
            *(float4*)&av[4] = *(const float4*)&As[k][m0+4];
            *(float4*)&bv[0] = *(const float4*)&Bs[k][n0];
            *(float4*)&bv[4] = *(const float4*)&Bs[k][n0+4];
            #pragma unroll
            for (int i=0;i<8;i++)
                #pragma unroll
                for (int j=0;j<8;j++)
                    acc[i][j] += av[i]*bv[j];
        }
        __syncthreads();
    }
    float* g = G + (size_t)chunk*16384;
    #pragma unroll
    for (int i=0;i<8;i++){
        float4 o0; o0.x=acc[i][0]; o0.y=acc[i][1]; o0.z=acc[i][2]; o0.w=acc[i][3];
        float4 o1; o1.x=acc[i][4]; o1.y=acc[i][5]; o1.z=acc[i][6]; o1.w=acc[i][7];
        *(float4*)(g + (size_t)(m0+i)*128 + n0)   = o0;
        *(float4*)(g + (size_t)(m0+i)*128 + n0+4) = o1;
    }
}

// ---------------------------------------------------------------------------
// Scan: surprise = -G; momentum/update first-order recurrences over n=0..63.
// In place: G[chunk] <- winit + update[chunk]. 1 thread per (bh, i, j).
// ---------------------------------------------------------------------------
__global__ __launch_bounds__(256) void k_scan(
    float* __restrict__ G, const float* __restrict__ winit,
    const float* __restrict__ am, const float* __restrict__ dec)
{
    int gidx = blockIdx.x*256 + threadIdx.x;
    int bh = gidx >> 14;
    int rem = gidx & 16383;
    float wv = winit[rem];
    float mom = 0.f, upd = 0.f;
    for (int n=0;n<64;n++){
        size_t idx = ((size_t)(bh*64 + n))*16384 + rem;
        float sur = -G[idx];
        float a = am[bh*64+n];
        float d = dec[bh*64+n];
        mom = (n==0) ? sur : a*mom + sur;
        upd = (n==0) ? mom : (1.f - d)*upd + mom;
        G[idx] = wv + upd;
    }
}

// ---------------------------------------------------------------------------
// Retrieve: per-chunk out = silu(Q @ W0t) @ W1t, then multihead-RMSNorm *
// (gamma+1) * gate, written to out_pre (B,L,H*DH). One block per chunk.
// ---------------------------------------------------------------------------
__global__ __launch_bounds__(256) void k_retrieve(
    const float* __restrict__ Q, const float* __restrict__ W0t,
    const float* __restrict__ W1t, const float* __restrict__ gamma,
    const float* __restrict__ gate, float* __restrict__ out_pre)
{
    int chunk = blockIdx.x;
    int bh = chunk >> 6, n = chunk & 63;
    int b = bh >> 2, h = bh & 3;
    __shared__ float Xs[128][68];    // transposed operand [k][m]
    __shared__ float Ws[32][132];
    __shared__ float rstd_s[64];
    int tid = threadIdx.x;
    const float* Qb = Q + (size_t)chunk*64*128;
    for (int i=tid; i<64*128; i+=256){
        int c = i>>7, d = i&127;
        Xs[d][c] = Qb[i];
    }
    int m0 = (tid>>4)<<2;   // 4 rows (of 64)
    int n0 = (tid&15)<<3;   // 8 cols (of 128)
    const float* W0c = W0t + (size_t)chunk*16384;
    const float* W1c = W1t + (size_t)chunk*16384;
    float acc[4][8];
    #pragma unroll
    for (int i=0;i<4;i++)
        #pragma unroll
        for (int j=0;j<8;j++) acc[i][j]=0.f;
    for (int k0=0;k0<128;k0+=32){
        for (int i=tid*4; i<32*128; i+=1024){
            int kr = i>>7, c = i&127;
            *(float4*)&Ws[kr][c] = *(const float4*)(W0c + (size_t)(k0+kr)*128 + c);
        }
        __syncthreads();
        #pragma unroll
        for (int k=0;k<32;k++){
            float4 at = *(const float4*)&Xs[k0+k][m0];
            float av[4] = {at.x, at.y, at.z, at.w};
            float bv[8];
            *(float4*)&bv[0] = *(const float4*)&Ws[k][n0];
            *(float4*)&bv[4] = *(const float4*)&Ws[k][n0+4];
            #pragma unroll
            for (int i=0;i<4;i++)
                #pragma unroll
                for (int j=0;j<8;j++) acc[i][j] += av[i]*bv[j];
        }
        __syncthreads();
    }
    // silu -> Xs (hidden transposed)
    #pragma unroll
    for (int i=0;i<4;i++)
        #pragma unroll
        for (int j=0;j<8;j++)
            Xs[n0+j][m0+i] = siluf_(acc[i][j]);
    __syncthreads();
    float acc2[4][8];
    #pragma unroll
    for (int i=0;i<4;i++)
        #pragma unroll
        for (int j=0;j<8;j++) acc2[i][j]=0.f;
    for (int k0=0;k0<128;k0+=32){
        for (int i=tid*4; i<32*128; i+=1024){
            int kr = i>>7, c = i&127;
            *(float4*)&Ws[kr][c] = *(const float4*)(W1c + (size_t)(k0+kr)*128 + c);
        }
        __syncthreads();
        #pragma unroll
        for (int k=0;k<32;k++){
            float4 at = *(const float4*)&Xs[k0+k][m0];
            float av[4] = {at.x, at.y, at.z, at.w};
            float bv[8];
            *(float4*)&bv[0] = *(const float4*)&Ws[k][n0];
            *(float4*)&bv[4] = *(const float4*)&Ws[k][n0+4];
            #pragma unroll
            for (int i=0;i<4;i++)
                #pragma unroll
                for (int j=0;j<8;j++) acc2[i][j] += av[i]*bv[j];
        }
        __syncthreads();
    }
    // stash result rows in LDS (alias Xs, stride 132) for row rmsnorm
    float* ol = &Xs[0][0];
    #pragma unroll
    for (int i=0;i<4;i++)
        #pragma unroll
        for (int j=0;j<8;j++)
            ol[(size_t)(m0+i)*132 + (n0+j)] = acc2[i][j];
    __syncthreads();
    if (tid < 64){
        float ssum = 0.f;
        for (int d2=0; d2<128; d2++){ float x = ol[(size_t)tid*132 + d2]; ssum += x*x; }
        rstd_s[tid] = rsqrtf(ssum*(1.0f/128.0f) + EPS_C);
    }
    __syncthreads();
    int tbase = n*64;
    for (int i2=tid; i2<64*128; i2+=256){
        int m = i2>>7, d2 = i2&127;
        int tok = tbase + m;
        float g_ = gate[((size_t)b*LL + tok)*4 + h];
        float val = ol[(size_t)m*132 + d2] * rstd_s[m] * (gamma[h*128 + d2] + 1.0f) * g_;
        out_pre[((size_t)b*LL + tok)*512 + h*128 + d2] = val;
    }
}

// ---------------------------------------------------------------------------
// Fill first 63 tokens of each batch with empty_embed.
// ---------------------------------------------------------------------------
__global__ void k_empty(const float* __restrict__ e, float* __restrict__ out){
    int i = blockIdx.x*256 + threadIdx.x;
    if (i >= BB*63*DIMM) return;
    int b = i / (63*DIMM);
    int r = i % (63*DIMM);
    int t = r / DIMM, d = r % DIMM;
    out[((size_t)b*LL + t)*DIMM + d] = e[d];
}

extern "C" void kernel_launch(void* const* d_in, const int* in_sizes, int n_in,
                              void* d_out, int out_size, void* d_ws, size_t ws_size,
                              hipStream_t stream)
{
    (void)in_sizes; (void)n_in; (void)out_size; (void)ws_size;
    const float* seq    = (const float*)d_in[0];
    const float* sscale = (const float*)d_in[1];
    const float* rscale = (const float*)d_in[2];
    const float* w_q    = (const float*)d_in[3];
    const float* w_kv   = (const float*)d_in[4];
    const float* w_ada  = (const float*)d_in[5];
    const float* w_mom  = (const float*)d_in[6];
    const float* w_dec  = (const float*)d_in[7];
    const float* w0     = (const float*)d_in[8];
    const float* w1     = (const float*)d_in[9];
    const float* gamma  = (const float*)d_in[10];
    const float* w_gate = (const float*)d_in[11];
    const float* w_comb = (const float*)d_in[12];
    const float* empty  = (const float*)d_in[13];
    float* out = (float*)d_out;
    float* w = (float*)d_ws;

    // workspace layout (floats); buffers are reused across phases:
    float* sbuf  = w;               // 4194304: s -> H -> dH -> Q
    float* rcbuf = w + 4194304;     // 4194304: shifted retrieve-norm
    float* kbuf  = w + 8388608;     // 4194304: keys -> out_pre
    float* vbuf  = w + 12582912;    // 4194304: vals -> dP (in place)
    float* g0buf = w + 16777216;    // 8388608: g0 -> w0_t
    float* g1buf = w + 25165824;    // 8388608: g1 -> w1_t
    float* lrbuf = w + 33554432;    // 32768
    float* ambuf = w + 33587200;    // 512
    float* dcbuf = w + 33587712;    // 512
    float* gtbuf = w + 33588224;    // 32768

    k_rmsnorm<<<TOK/4, 256, 0, stream>>>(seq, sscale, rscale, w_ada, w_gate,
                                         sbuf, rcbuf, lrbuf, gtbuf);
    k_chunkstats<<<BB*NNN, 256, 0, stream>>>(sbuf, w_mom, w_dec, ambuf, dcbuf);
    // kv = s @ w_kv -> keys/vals head-major
    k_gemm<<<dim3(8, 64), 256, 0, stream>>>(sbuf, w_kv, kbuf, vbuf, nullptr,
                                            8192, 1024, 512, 0, 0, 1);
    // H = keys @ w0   (into sbuf)
    k_gemm<<<dim3(1, 256), 256, 0, stream>>>(kbuf, w0, sbuf, nullptr, nullptr,
                                             32768, 128, 128, 0, 0, 0);
    // dP = (2/128)*lr*(silu(H) @ w1 - vals)   (in place over vals)
    k_gemm<<<dim3(1, 256), 256, 0, stream>>>(sbuf, w1, vbuf, nullptr, lrbuf,
                                             32768, 128, 128, 1, 0, 2);
    // g1 = silu(H)^T @ dP  per chunk
    k_chunk_grad<<<NCH, 256, 0, stream>>>(sbuf, vbuf, g1buf, 1);
    // dH = (dP @ w1^T) * silu'(H)   (in place over H)
    k_gemm<<<dim3(1, 256), 256, 0, stream>>>(vbuf, w1, sbuf, nullptr, nullptr,
                                             32768, 128, 128, 0, 1, 3);
    // g0 = keys^T @ dH  per chunk
    k_chunk_grad<<<NCH, 256, 0, stream>>>(kbuf, sbuf, g0buf, 0);
    // scans -> w0_t / w1_t in place
    k_scan<<<512, 256, 0, stream>>>(g0buf, w0, ambuf, dcbuf);
    k_scan<<<512, 256, 0, stream>>>(g1buf, w1, ambuf, dcbuf);
    // Q = rc @ w_q -> head-major (into sbuf)
    k_gemm<<<dim3(4, 64), 256, 0, stream>>>(rcbuf, w_q, sbuf, nullptr, nullptr,
                                            8192, 512, 512, 0, 0, 5);
    // retrieve MLP + MH-rmsnorm + gate -> out_pre (into kbuf)
    k_retrieve<<<NCH, 256, 0, stream>>>(sbuf, g0buf, g1buf, gamma, gtbuf, kbuf);
    // combine heads + 63-token shift
    k_gemm<<<dim3(4, 64), 256, 0, stream>>>(kbuf, w_comb, out, nullptr, nullptr,
                                            8192, 512, 512, 0, 0, 4);
    k_empty<<<(BB*63*DIMM + 255)/256, 256, 0, stream>>>(empty, out);
}

// Round 2
// 256.680 us; speedup vs baseline: 2.4973x; 2.4973x over previous
//
#include <hip/hip_runtime.h>

typedef unsigned short ushort_t;
typedef __bf16 bf16x8 __attribute__((ext_vector_type(8)));
typedef float f32x4 __attribute__((ext_vector_type(4)));
typedef const __attribute__((address_space(1))) void* gas1_t;
typedef __attribute__((address_space(3))) void* las3_t;

#define BB 2
#define LL 4096
#define DIMM 512
#define TOK (BB*LL)      // 8192
#define ROWS 32768       // BH*L head-major rows
#define NCH 512          // BH*N chunks
#define MAX_LR_C 0.01f
#define EPS_C 1e-6f

__device__ __forceinline__ float sigmoidf_(float x){ return 1.0f/(1.0f + __expf(-x)); }
__device__ __forceinline__ ushort_t f2bf(float f){
    unsigned u = __builtin_bit_cast(unsigned, f);
    unsigned r = u + 0x7FFFu + ((u>>16)&1u);
    return (ushort_t)(r>>16);
}
__device__ __forceinline__ float bf2f(ushort_t h){
    unsigned u = ((unsigned)h)<<16; return __builtin_bit_cast(float, u);
}

// ---------------------------------------------------------------------------
// Weight conversion/transpose to bf16 (one pass).
// ---------------------------------------------------------------------------
__global__ __launch_bounds__(256) void k_convert(
    const float* __restrict__ w_kv, const float* __restrict__ w_q,
    const float* __restrict__ w_comb, const float* __restrict__ w0,
    const float* __restrict__ w1,
    ushort_t* __restrict__ w_kvT, ushort_t* __restrict__ w_qT,
    ushort_t* __restrict__ w_combT, ushort_t* __restrict__ w0T_b,
    ushort_t* __restrict__ w1T_b, ushort_t* __restrict__ w1_b,
    float* __restrict__ w0T_f, float* __restrict__ w1T_f)
{
    int i = blockIdx.x*256 + threadIdx.x;
    if (i < 524288){ int n=i>>9, k=i&511; w_kvT[i] = f2bf(w_kv[k*1024+n]); return; }
    i -= 524288;
    if (i < 262144){ int n=i>>9, k=i&511; w_qT[i] = f2bf(w_q[k*512+n]); return; }
    i -= 262144;
    if (i < 262144){ int n=i>>9, k=i&511; w_combT[i] = f2bf(w_comb[k*512+n]); return; }
    i -= 262144;
    if (i < 16384){ int n=i>>7, k=i&127; float v=w0[k*128+n]; w0T_b[i]=f2bf(v); w0T_f[i]=v; return; }
    i -= 16384;
    if (i < 16384){ int n=i>>7, k=i&127; float v=w1[k*128+n]; w1T_b[i]=f2bf(v); w1T_f[i]=v; return; }
    i -= 16384;
    if (i < 16384){ w1_b[i] = f2bf(w1[i]); }
}

// ---------------------------------------------------------------------------
// RMSNorm (store & retrieve, bf16 out), adaptive_lr, gate. One wave/token.
// rc & gate stored PRE-SHIFTED by 63 tokens; tail rows zero / sigmoid(0).
// ---------------------------------------------------------------------------
__global__ __launch_bounds__(256) void k_rmsnorm(
    const float* __restrict__ seq, const float* __restrict__ sscale,
    const float* __restrict__ rscale, const float* __restrict__ w_ada,
    const float* __restrict__ w_gate, ushort_t* __restrict__ s,
    ushort_t* __restrict__ rc, float* __restrict__ lr, float* __restrict__ gate)
{
    int tok = blockIdx.x*4 + (threadIdx.x>>6);
    int lane = threadIdx.x & 63;
    int b = tok >> 12, t = tok & 4095;
    const float* x = seq + (size_t)tok*DIMM;
    float v[8]; float ss = 0.f;
    #pragma unroll
    for (int j=0;j<8;j++){ v[j] = x[lane + 64*j]; ss += v[j]*v[j]; }
    #pragma unroll
    for (int m=1;m<64;m<<=1) ss += __shfl_xor(ss, m, 64);
    float rstd = rsqrtf(ss * (1.0f/DIMM) + EPS_C);
    float sv[8], rv[8];
    float pa[4] = {0,0,0,0}, pg[4] = {0,0,0,0};
    #pragma unroll
    for (int j=0;j<8;j++){
        int d = lane + 64*j;
        float nv = v[j]*rstd;
        sv[j] = nv * sscale[d];
        rv[j] = nv * rscale[d];
        #pragma unroll
        for (int h=0;h<4;h++){
            pa[h] += sv[j]*w_ada[d*4+h];
            pg[h] += rv[j]*w_gate[d*4+h];
        }
    }
    ushort_t* srow = s + (size_t)tok*DIMM;
    #pragma unroll
    for (int j=0;j<8;j++) srow[lane+64*j] = f2bf(sv[j]);
    if (t >= 63){
        ushort_t* rrow = rc + ((size_t)b*LL + (t-63))*DIMM;
        #pragma unroll
        for (int j=0;j<8;j++) rrow[lane+64*j] = f2bf(rv[j]);
    } else {
        ushort_t* rrow = rc + ((size_t)b*LL + (LL-63+t))*DIMM;
        #pragma unroll
        for (int j=0;j<8;j++) rrow[lane+64*j] = 0;
    }
    #pragma unroll
    for (int h=0;h<4;h++){
        #pragma unroll
        for (int m=1;m<64;m<<=1){
            pa[h] += __shfl_xor(pa[h], m, 64);
            pg[h] += __shfl_xor(pg[h], m, 64);
        }
    }
    if (lane < 4){
        int h = lane;
        lr[((size_t)(b*4+h))*LL + t] = sigmoidf_(pa[h]) * MAX_LR_C;
        if (t >= 63) gate[((size_t)b*LL + (t-63))*4 + h] = sigmoidf_(pg[h]);
        else         gate[((size_t)b*LL + (LL-63+t))*4 + h] = 0.5f;
    }
}

// ---------------------------------------------------------------------------
// Chunk means -> ada_mom/decay. One block per (b,n).
// ---------------------------------------------------------------------------
__global__ __launch_bounds__(256) void k_chunkstats(
    const ushort_t* __restrict__ s, const float* __restrict__ w_mom,
    const float* __restrict__ w_dec, float* __restrict__ ada_mom,
    float* __restrict__ decay)
{
    int b = blockIdx.x >> 6, n = blockIdx.x & 63;
    float pm[4] = {0,0,0,0}, pd[4] = {0,0,0,0};
    #pragma unroll
    for (int rep=0; rep<2; rep++){
        int d = threadIdx.x + rep*256;
        const ushort_t* base = s + ((size_t)b*LL + n*64)*DIMM + d;
        float acc = 0.f;
        for (int c=0;c<64;c++) acc += bf2f(base[(size_t)c*DIMM]);
        float mean = acc * (1.0f/64.0f);
        #pragma unroll
        for (int h=0;h<4;h++){ pm[h] += mean*w_mom[d*4+h]; pd[h] += mean*w_dec[d*4+h]; }
    }
    #pragma unroll
    for (int h=0;h<4;h++){
        #pragma unroll
        for (int m=1;m<64;m<<=1){ pm[h]+=__shfl_xor(pm[h],m,64); pd[h]+=__shfl_xor(pd[h],m,64); }
    }
    __shared__ float lds[4][8];
    int wave = threadIdx.x>>6, lane = threadIdx.x&63;
    if (lane==0){
        #pragma unroll
        for (int h=0;h<4;h++){ lds[wave][h]=pm[h]; lds[wave][4+h]=pd[h]; }
    }
    __syncthreads();
    if (threadIdx.x < 8){
        float tot = lds[0][threadIdx.x]+lds[1][threadIdx.x]+lds[2][threadIdx.x]+lds[3][threadIdx.x];
        int h = threadIdx.x & 3;
        int bh = b*4 + h;
        if (threadIdx.x < 4) ada_mom[bh*64+n] = sigmoidf_(tot);
        else                 decay[bh*64+n]   = sigmoidf_(tot);
    }
}

// ---------------------------------------------------------------------------
// bf16 MFMA GEMM (m97 structure): 128x128 tile, BK=32, 4 waves, 4x4 16x16x32
// tiles per wave, global_load_lds width-16 staging. A: MxK bf16 row-major;
// BT: NxK bf16 row-major (pre-transposed B).
// MODE 0 kv:   O1=keys[t][d] hm, O2=keysT[d][t] chunk, O3=vals[t][d] hm
// MODE 1 H:    O1=silu(H), O2=siluHT chunk, O3=silu'(H)
// MODE 2 dP:   X1=vals, F1=lr;  dP=(2/128)*lr*(acc-vals); O1=dP, O2=dPT
// MODE 3 dH:   X1=sp; dH=acc*sp; O2=dHT chunk only
// MODE 4 Q:    O1=q[t][d] head-major
// MODE 5 comb: FO=d_out fp32 with +63 shift
// ---------------------------------------------------------------------------
template<int MODE>
__global__ __launch_bounds__(256) void k_mm(
    const ushort_t* __restrict__ A, const ushort_t* __restrict__ BT,
    ushort_t* __restrict__ O1, ushort_t* __restrict__ O2, ushort_t* __restrict__ O3,
    const ushort_t* __restrict__ X1, const float* __restrict__ F1,
    float* __restrict__ FO, int M, int N, int K)
{
    __shared__ ushort_t As[128*32];
    __shared__ ushort_t Bs[128*32];
    int tid = threadIdx.x;
    int w = tid>>6, l = tid&63;
    int row0 = blockIdx.y*128, col0 = blockIdx.x*128;
    int wm = (w>>1)*64, wn = (w&1)*64;
    int lr16 = l&15, q = l>>4;
    f32x4 acc[4][4] = {};
    int arow = l>>2;          // 0..15
    int akof = (l&3)<<3;      // 0/8/16/24
    const size_t rA0 = (size_t)(row0 + w*16 + arow)*(size_t)K + akof;
    const size_t rA1 = rA0 + (size_t)64*K;
    const size_t rB0 = (size_t)(col0 + w*16 + arow)*(size_t)K + akof;
    const size_t rB1 = rB0 + (size_t)64*K;
    for (int k0=0; k0<K; k0+=32){
        __builtin_amdgcn_global_load_lds((gas1_t)(const void*)(A + rA0 + k0),
                                         (las3_t)(void*)(As + w*512), 16, 0, 0);
        __builtin_amdgcn_global_load_lds((gas1_t)(const void*)(A + rA1 + k0),
                                         (las3_t)(void*)(As + 2048 + w*512), 16, 0, 0);
        __builtin_amdgcn_global_load_lds((gas1_t)(const void*)(BT + rB0 + k0),
                                         (las3_t)(void*)(Bs + w*512), 16, 0, 0);
        __builtin_amdgcn_global_load_lds((gas1_t)(const void*)(BT + rB1 + k0),
                                         (las3_t)(void*)(Bs + 2048 + w*512), 16, 0, 0);
        __syncthreads();
        bf16x8 af[4], bfv[4];
        #pragma unroll
        for (int i=0;i<4;i++){
            af[i]  = *(const bf16x8*)&As[(wm + i*16 + lr16)*32 + q*8];
            bfv[i] = *(const bf16x8*)&Bs[(wn + i*16 + lr16)*32 + q*8];
        }
        #pragma unroll
        for (int i=0;i<4;i++)
            #pragma unroll
            for (int j=0;j<4;j++)
                acc[i][j] = __builtin_amdgcn_mfma_f32_16x16x32_bf16(af[i], bfv[j], acc[i][j], 0,0,0);
        __syncthreads();
    }
    // epilogue
    #pragma unroll
    for (int i=0;i<4;i++){
        int trb = row0 + wm + i*16 + q*4;     // 4 consecutive rows trb..trb+3
        float lrv[4];
        if constexpr (MODE==2){
            lrv[0]=F1[trb]; lrv[1]=F1[trb+1]; lrv[2]=F1[trb+2]; lrv[3]=F1[trb+3];
        }
        #pragma unroll
        for (int j=0;j<4;j++){
            int tcol = col0 + wn + j*16 + lr16;
            f32x4 v = acc[i][j];
            if constexpr (MODE==0){
                int bb = trb>>12, l0 = trb&4095;
                int hh = (tcol>>7)&3, dd = tcol&127;
                size_t hm = ((size_t)(bb*4+hh)*LL + l0)*128 + dd;
                ushort_t e0=f2bf(v[0]), e1=f2bf(v[1]), e2=f2bf(v[2]), e3=f2bf(v[3]);
                if (tcol < 512){
                    O1[hm]=e0; O1[hm+128]=e1; O1[hm+256]=e2; O1[hm+384]=e3;
                    int ch = (bb*4+hh)*64 + (l0>>6);
                    ushort4 pk; pk.x=e0; pk.y=e1; pk.z=e2; pk.w=e3;
                    *(ushort4*)&O2[(size_t)ch*8192 + dd*64 + (l0&63)] = pk;
                } else {
                    O3[hm]=e0; O3[hm+128]=e1; O3[hm+256]=e2; O3[hm+384]=e3;
                }
            } else if constexpr (MODE==1){
                size_t idx = (size_t)trb*128 + tcol;
                int ch = trb>>6;
                ushort4 pk;
                #pragma unroll
                for (int r=0;r<4;r++){
                    float hv = v[r];
                    float sg = sigmoidf_(hv);
                    float si = hv*sg;
                    float sp = sg*(1.f + hv*(1.f-sg));
                    ushort_t eb = f2bf(si);
                    O1[idx + (size_t)r*128] = eb;
                    O3[idx + (size_t)r*128] = f2bf(sp);
                    if (r==0) pk.x=eb; else if (r==1) pk.y=eb; else if (r==2) pk.z=eb; else pk.w=eb;
                }
                *(ushort4*)&O2[(size_t)ch*8192 + tcol*64 + (trb&63)] = pk;
            } else if constexpr (MODE==2){
                size_t idx = (size_t)trb*128 + tcol;
                int ch = trb>>6;
                ushort4 pk;
                #pragma unroll
                for (int r=0;r<4;r++){
                    float val = bf2f(X1[idx + (size_t)r*128]);
                    float dp = 0.015625f * lrv[r] * (v[r] - val);
                    ushort_t eb = f2bf(dp);
                    O1[idx + (size_t)r*128] = eb;
                    if (r==0) pk.x=eb; else if (r==1) pk.y=eb; else if (r==2) pk.z=eb; else pk.w=eb;
                }
                *(ushort4*)&O2[(size_t)ch*8192 + tcol*64 + (trb&63)] = pk;
            } else if constexpr (MODE==3){
                size_t idx = (size_t)trb*128 + tcol;
                int ch = trb>>6;
                ushort4 pk;
                #pragma unroll
                for (int r=0;r<4;r++){
                    float dh = v[r] * bf2f(X1[idx + (size_t)r*128]);
                    ushort_t eb = f2bf(dh);
                    if (r==0) pk.x=eb; else if (r==1) pk.y=eb; else if (r==2) pk.z=eb; else pk.w=eb;
                }
                *(ushort4*)&O2[(size_t)ch*8192 + tcol*64 + (trb&63)] = pk;
            } else if constexpr (MODE==4){
                int bb = trb>>12, l0 = trb&4095;
                int hh = tcol>>7, dd = tcol&127;
                size_t hm = ((size_t)(bb*4+hh)*LL + l0)*128 + dd;
                O1[hm]=f2bf(v[0]); O1[hm+128]=f2bf(v[1]); O1[hm+256]=f2bf(v[2]); O1[hm+384]=f2bf(v[3]);
            } else { // 5
                int bb = trb>>12;
                #pragma unroll
                for (int r=0;r<4;r++){
                    int t = (trb&4095)+r;
                    if (t < LL-63)
                        FO[((size_t)bb*LL + t + 63)*DIMM + tcol] = v[r];
                }
            }
        }
    }
}

// ---------------------------------------------------------------------------
// Per-chunk 128x128 outer-product gradient (transposed): D = At * Bt^T over
// t=0..63, with At/Bt stored [d][t] bf16. Output bf16 G[chunk][128][128].
// ---------------------------------------------------------------------------
__global__ __launch_bounds__(256) void k_cgrad(
    const ushort_t* __restrict__ At, const ushort_t* __restrict__ Bt,
    ushort_t* __restrict__ G)
{
    int chunk = blockIdx.x;
    __shared__ ushort_t Ap[128*72];
    __shared__ ushort_t Bp[128*72];
    int tid = threadIdx.x;
    const ushort_t* Ab = At + (size_t)chunk*8192;
    const ushort_t* Bb = Bt + (size_t)chunk*8192;
    #pragma unroll
    for (int it=0; it<4; it++){
        int i = tid*8 + it*2048;
        int row = i>>6, c = i&63;
        *(uint4*)&Ap[row*72+c] = *(const uint4*)&Ab[i];
        *(uint4*)&Bp[row*72+c] = *(const uint4*)&Bb[i];
    }
    __syncthreads();
    int w=tid>>6, l=tid&63, lr16=l&15, q=l>>4;
    int wm=(w>>1)*64, wn=(w&1)*64;
    f32x4 acc[4][4] = {};
    #pragma unroll
    for (int k0=0;k0<64;k0+=32){
        bf16x8 af[4], bfv[4];
        #pragma unroll
        for (int i=0;i<4;i++){
            af[i]  = *(const bf16x8*)&Ap[(wm+i*16+lr16)*72 + k0 + q*8];
            bfv[i] = *(const bf16x8*)&Bp[(wn+i*16+lr16)*72 + k0 + q*8];
        }
        #pragma unroll
        for (int i=0;i<4;i++)
            #pragma unroll
            for (int j=0;j<4;j++)
                acc[i][j] = __builtin_amdgcn_mfma_f32_16x16x32_bf16(af[i], bfv[j], acc[i][j], 0,0,0);
    }
    ushort_t* g = G + (size_t)chunk*16384;
    #pragma unroll
    for (int i=0;i<4;i++){
        int rr = wm + i*16 + q*4;
        #pragma unroll
        for (int j=0;j<4;j++){
            int cc = wn + j*16 + lr16;
            #pragma unroll
            for (int r=0;r<4;r++)
                g[(size_t)(rr+r)*128 + cc] = f2bf(acc[i][j][r]);
        }
    }
}

// ---------------------------------------------------------------------------
// Linear-recurrence scans over 64 chunks; wt = winitT + update (bf16 out).
// ---------------------------------------------------------------------------
__global__ __launch_bounds__(256) void k_scan(
    const ushort_t* __restrict__ G, const float* __restrict__ winitT,
    const float* __restrict__ am, const float* __restrict__ dec,
    ushort_t* __restrict__ wt)
{
    int gidx = blockIdx.x*256 + threadIdx.x;
    int bh = gidx >> 14;
    int rem = gidx & 16383;
    float wv = winitT[rem];
    float mom = 0.f, upd = 0.f;
    for (int n=0;n<64;n++){
        size_t idx = ((size_t)(bh*64 + n))*16384 + rem;
        float sur = -bf2f(G[idx]);
        float a = am[bh*64+n];
        float d = dec[bh*64+n];
        mom = (n==0) ? sur : a*mom + sur;
        upd = (n==0) ? mom : (1.f - d)*upd + mom;
        wt[idx] = f2bf(wv + upd);
    }
}

// ---------------------------------------------------------------------------
// Retrieve: per chunk, O2 = silu(Q @ w0t) @ w1t with wt stored transposed
// ([n][k] = B-fragment layout), then per-row rmsnorm * (gamma+1) * gate.
// ---------------------------------------------------------------------------
__global__ __launch_bounds__(256) void k_retr(
    const ushort_t* __restrict__ Q, const ushort_t* __restrict__ W0t,
    const ushort_t* __restrict__ W1t, const float* __restrict__ gamma,
    const float* __restrict__ gate, ushort_t* __restrict__ out_pre)
{
    int chunk = blockIdx.x;
    int bh = chunk>>6, n = chunk&63, b = bh>>2, h = bh&3;
    __shared__ ushort_t Qs[64*136];
    __shared__ ushort_t Ws[128*136];
    __shared__ ushort_t O1s[64*136];
    int tid = threadIdx.x;
    const ushort_t* Qb = Q + (size_t)chunk*8192;
    #pragma unroll
    for (int it=0; it<4; it++){
        int i = tid*8 + it*2048;
        int row=i>>7, c=i&127;
        *(uint4*)&Qs[row*136+c] = *(const uint4*)&Qb[i];
    }
    const ushort_t* W0b = W0t + (size_t)chunk*16384;
    #pragma unroll
    for (int it=0; it<8; it++){
        int i = tid*8 + it*2048;
        int row=i>>7, c=i&127;
        *(uint4*)&Ws[row*136+c] = *(const uint4*)&W0b[i];
    }
    __syncthreads();
    int w=tid>>6, l=tid&63, lr16=l&15, q=l>>4;
    f32x4 acc[8] = {};
    #pragma unroll
    for (int k0=0;k0<128;k0+=32){
        bf16x8 af = *(const bf16x8*)&Qs[(w*16+lr16)*136 + k0 + q*8];
        #pragma unroll
        for (int j=0;j<8;j++){
            bf16x8 bv = *(const bf16x8*)&Ws[(j*16+lr16)*136 + k0 + q*8];
            acc[j] = __builtin_amdgcn_mfma_f32_16x16x32_bf16(af, bv, acc[j], 0,0,0);
        }
    }
    // silu -> O1s [t][dm]
    #pragma unroll
    for (int j=0;j<8;j++){
        #pragma unroll
        for (int r=0;r<4;r++){
            float hv = acc[j][r];
            float sg = sigmoidf_(hv);
            O1s[(w*16+q*4+r)*136 + j*16+lr16] = f2bf(hv*sg);
        }
    }
    __syncthreads();
    const ushort_t* W1b = W1t + (size_t)chunk*16384;
    #pragma unroll
    for (int it=0; it<8; it++){
        int i = tid*8 + it*2048;
        int row=i>>7, c=i&127;
        *(uint4*)&Ws[row*136+c] = *(const uint4*)&W1b[i];
    }
    __syncthreads();
    f32x4 acc2[8] = {};
    #pragma unroll
    for (int k0=0;k0<128;k0+=32){
        bf16x8 af = *(const bf16x8*)&O1s[(w*16+lr16)*136 + k0 + q*8];
        #pragma unroll
        for (int j=0;j<8;j++){
            bf16x8 bv = *(const bf16x8*)&Ws[(j*16+lr16)*136 + k0 + q*8];
            acc2[j] = __builtin_amdgcn_mfma_f32_16x16x32_bf16(af, bv, acc2[j], 0,0,0);
        }
    }
    // per-row rmsnorm over 128 cols (rows = q*4+r within wave's 16)
    float ssq[4] = {0,0,0,0};
    #pragma unroll
    for (int j=0;j<8;j++)
        #pragma unroll
        for (int r=0;r<4;r++) ssq[r] += acc2[j][r]*acc2[j][r];
    #pragma unroll
    for (int r=0;r<4;r++){
        ssq[r] += __shfl_xor(ssq[r], 1, 64);
        ssq[r] += __shfl_xor(ssq[r], 2, 64);
        ssq[r] += __shfl_xor(ssq[r], 4, 64);
        ssq[r] += __shfl_xor(ssq[r], 8, 64);
    }
    int tok0 = n*64 + w*16 + q*4;
    #pragma unroll
    for (int r=0;r<4;r++){
        float rstd = rsqrtf(ssq[r]*(1.0f/128.0f) + EPS_C);
        float gv = gate[((size_t)b*LL + tok0 + r)*4 + h];
        #pragma unroll
        for (int j=0;j<8;j++){
            int d = j*16 + lr16;
            float val = acc2[j][r]*rstd*(gamma[h*128+d]+1.0f)*gv;
            out_pre[((size_t)b*LL + tok0 + r)*DIMM + h*128 + d] = f2bf(val);
        }
    }
}

__global__ void k_empty(const float* __restrict__ e, float* __restrict__ out){
    int i = blockIdx.x*256 + threadIdx.x;
    if (i >= BB*63*DIMM) return;
    int b = i / (63*DIMM);
    int r = i % (63*DIMM);
    int t = r / DIMM, d = r % DIMM;
    out[((size_t)b*LL + t)*DIMM + d] = e[d];
}

extern "C" void kernel_launch(void* const* d_in, const int* in_sizes, int n_in,
                              void* d_out, int out_size, void* d_ws, size_t ws_size,
                              hipStream_t stream)
{
    (void)in_sizes; (void)n_in; (void)out_size; (void)ws_size;
    const float* seq    = (const float*)d_in[0];
    const float* sscale = (const float*)d_in[1];
    const float* rscale = (const float*)d_in[2];
    const float* w_q    = (const float*)d_in[3];
    const float* w_kv   = (const float*)d_in[4];
    const float* w_ada  = (const float*)d_in[5];
    const float* w_mom  = (const float*)d_in[6];
    const float* w_dec  = (const float*)d_in[7];
    const float* w0     = (const float*)d_in[8];
    const float* w1     = (const float*)d_in[9];
    const float* gamma  = (const float*)d_in[10];
    const float* w_gate = (const float*)d_in[11];
    const float* w_comb = (const float*)d_in[12];
    const float* empty  = (const float*)d_in[13];
    float* out = (float*)d_out;
    char* wsb = (char*)d_ws;

    // byte offsets (8.4 MB bf16 row buffers, overlaid across phases)
    ushort_t* bufA = (ushort_t*)(wsb + 0);          // s -> siluH -> dHT
    ushort_t* bufB = (ushort_t*)(wsb + 8388608);    // keys -> dP -> out_pre
    ushort_t* bufC = (ushort_t*)(wsb + 16777216);   // vals -> q
    ushort_t* bufD = (ushort_t*)(wsb + 25165824);   // dPT
    ushort_t* bufE = (ushort_t*)(wsb + 33554432);   // keysT
    ushort_t* bufF = (ushort_t*)(wsb + 41943040);   // siluHT
    ushort_t* bufG = (ushort_t*)(wsb + 50331648);   // sp = silu'(H)
    ushort_t* bufH = (ushort_t*)(wsb + 58720256);   // rc (shifted)
    ushort_t* Gbuf  = (ushort_t*)(wsb + 67108864);  // 16.8MB, g1T then g0T
    ushort_t* wt1T  = (ushort_t*)(wsb + 83886080);  // 16.8MB
    ushort_t* wt0T  = (ushort_t*)(wsb + 100663296); // 16.8MB
    ushort_t* w_kvT   = (ushort_t*)(wsb + 117440512);
    ushort_t* w_qT    = (ushort_t*)(wsb + 118489088);
    ushort_t* w_combT = (ushort_t*)(wsb + 119013376);
    ushort_t* w0T_b   = (ushort_t*)(wsb + 119537664);
    ushort_t* w1T_b   = (ushort_t*)(wsb + 119570432);
    ushort_t* w1_b    = (ushort_t*)(wsb + 119603200);
    float* w0T_f = (float*)(wsb + 119635968);
    float* w1T_f = (float*)(wsb + 119701504);
    float* lrbuf = (float*)(wsb + 119767040);
    float* gtbuf = (float*)(wsb + 119898112);
    float* ambuf = (float*)(wsb + 120029184);
    float* dcbuf = (float*)(wsb + 120031232);

    k_convert<<<4288, 256, 0, stream>>>(w_kv, w_q, w_comb, w0, w1,
        w_kvT, w_qT, w_combT, w0T_b, w1T_b, w1_b, w0T_f, w1T_f);
    k_rmsnorm<<<TOK/4, 256, 0, stream>>>(seq, sscale, rscale, w_ada, w_gate,
        bufA, bufH, lrbuf, gtbuf);
    k_chunkstats<<<128, 256, 0, stream>>>(bufA, w_mom, w_dec, ambuf, dcbuf);
    // kv: keys(bufB) keysT(bufE) vals(bufC)
    k_mm<0><<<dim3(8,64), 256, 0, stream>>>(bufA, w_kvT, bufB, bufE, bufC,
        nullptr, nullptr, nullptr, 8192, 1024, 512);
    // H: siluH(bufA) siluHT(bufF) sp(bufG)
    k_mm<1><<<dim3(1,256), 256, 0, stream>>>(bufB, w0T_b, bufA, bufF, bufG,
        nullptr, nullptr, nullptr, ROWS, 128, 128);
    // dP: dP(bufB) dPT(bufD), reads vals(bufC), lr
    k_mm<2><<<dim3(1,256), 256, 0, stream>>>(bufA, w1T_b, bufB, bufD, nullptr,
        bufC, lrbuf, nullptr, ROWS, 128, 128);
    // g1T = dPT x siluHT
    k_cgrad<<<NCH, 256, 0, stream>>>(bufD, bufF, Gbuf);
    k_scan<<<512, 256, 0, stream>>>(Gbuf, w1T_f, ambuf, dcbuf, wt1T);
    // dH: dHT(bufA), reads dP(bufB), sp(bufG)
    k_mm<3><<<dim3(1,256), 256, 0, stream>>>(bufB, w1_b, nullptr, bufA, nullptr,
        bufG, nullptr, nullptr, ROWS, 128, 128);
    // g0T = dHT x keysT
    k_cgrad<<<NCH, 256, 0, stream>>>(bufA, bufE, Gbuf);
    k_scan<<<512, 256, 0, stream>>>(Gbuf, w0T_f, ambuf, dcbuf, wt0T);
    // Q: q(bufC)
    k_mm<4><<<dim3(4,64), 256, 0, stream>>>(bufH, w_qT, bufC, nullptr, nullptr,
        nullptr, nullptr, nullptr, 8192, 512, 512);
    // retrieve -> out_pre(bufB)
    k_retr<<<NCH, 256, 0, stream>>>(bufC, wt0T, wt1T, gamma, gtbuf, bufB);
    // combine -> d_out (shifted)
    k_mm<5><<<dim3(4,64), 256, 0, stream>>>(bufB, w_combT, nullptr, nullptr, nullptr,
        nullptr, nullptr, out, 8192, 512, 512);
    k_empty<<<252, 256, 0, stream>>>(empty, out);
}

// Round 3
// 214.435 us; speedup vs baseline: 2.9892x; 1.1970x over previous
//
#include <hip/hip_runtime.h>

typedef unsigned short ushort_t;
typedef __bf16 bf16x8 __attribute__((ext_vector_type(8)));
typedef float f32x4 __attribute__((ext_vector_type(4)));
typedef const __attribute__((address_space(1))) void* gas1_t;
typedef __attribute__((address_space(3))) void* las3_t;

#define BB 2
#define LL 4096
#define DIMM 512
#define TOK (BB*LL)      // 8192
#define ROWS 32768       // BH*L head-major rows
#define NCH 512          // BH*N chunks
#define MAX_LR_C 0.01f
#define EPS_C 1e-6f

__device__ __forceinline__ float sigmoidf_(float x){ return 1.0f/(1.0f + __expf(-x)); }
__device__ __forceinline__ ushort_t f2bf(float f){
    unsigned u = __builtin_bit_cast(unsigned, f);
    unsigned r = u + 0x7FFFu + ((u>>16)&1u);
    return (ushort_t)(r>>16);
}
__device__ __forceinline__ float bf2f(ushort_t h){
    unsigned u = ((unsigned)h)<<16; return __builtin_bit_cast(float, u);
}

// swizzled LDS offsets (element units, bf16): 2-way max bank aliasing
__device__ __forceinline__ int sw64x128(int t, int d){
    return (t<<7) | ((((d>>3) ^ (t&15))<<3) | (d&7));
}
__device__ __forceinline__ int sw128x64(int x, int t){
    return (x<<6) | ((((t>>3) ^ (x&7))<<3) | (t&7));
}

// ---------------------------------------------------------------------------
// Weight conversion/transpose to bf16 (one pass).
// ---------------------------------------------------------------------------
__global__ __launch_bounds__(256) void k_convert(
    const float* __restrict__ w_kv, const float* __restrict__ w_q,
    const float* __restrict__ w_comb, const float* __restrict__ w0,
    const float* __restrict__ w1,
    ushort_t* __restrict__ w_kvT, ushort_t* __restrict__ w_qT,
    ushort_t* __restrict__ w_combT, ushort_t* __restrict__ w0T_b,
    ushort_t* __restrict__ w1T_b, ushort_t* __restrict__ w1row_b,
    float* __restrict__ w0T_f, float* __restrict__ w1T_f)
{
    int i = blockIdx.x*256 + threadIdx.x;
    if (i < 524288){ int n=i>>9, k=i&511; w_kvT[i] = f2bf(w_kv[k*1024+n]); return; }
    i -= 524288;
    if (i < 262144){ int n=i>>9, k=i&511; w_qT[i] = f2bf(w_q[k*512+n]); return; }
    i -= 262144;
    if (i < 262144){ int n=i>>9, k=i&511; w_combT[i] = f2bf(w_comb[k*512+n]); return; }
    i -= 262144;
    if (i < 16384){ int n=i>>7, k=i&127; float v=w0[k*128+n]; w0T_b[i]=f2bf(v); w0T_f[i]=v; return; }
    i -= 16384;
    if (i < 16384){ int n=i>>7, k=i&127; float v=w1[k*128+n]; w1T_b[i]=f2bf(v); w1T_f[i]=v; return; }
    i -= 16384;
    if (i < 16384){ w1row_b[i] = f2bf(w1[i]); }
}

// ---------------------------------------------------------------------------
// RMSNorm (store & retrieve, bf16 out), adaptive_lr, gate. One wave/token.
// rc & gate stored PRE-SHIFTED by 63 tokens; tail rows zero / sigmoid(0).
// ---------------------------------------------------------------------------
__global__ __launch_bounds__(256) void k_rmsnorm(
    const float* __restrict__ seq, const float* __restrict__ sscale,
    const float* __restrict__ rscale, const float* __restrict__ w_ada,
    const float* __restrict__ w_gate, ushort_t* __restrict__ s,
    ushort_t* __restrict__ rc, float* __restrict__ lr, float* __restrict__ gate)
{
    int tok = blockIdx.x*4 + (threadIdx.x>>6);
    int lane = threadIdx.x & 63;
    int b = tok >> 12, t = tok & 4095;
    const float* x = seq + (size_t)tok*DIMM;
    float v[8]; float ss = 0.f;
    #pragma unroll
    for (int j=0;j<8;j++){ v[j] = x[lane + 64*j]; ss += v[j]*v[j]; }
    #pragma unroll
    for (int m=1;m<64;m<<=1) ss += __shfl_xor(ss, m, 64);
    float rstd = rsqrtf(ss * (1.0f/DIMM) + EPS_C);
    float sv[8], rv[8];
    float pa[4] = {0,0,0,0}, pg[4] = {0,0,0,0};
    #pragma unroll
    for (int j=0;j<8;j++){
        int d = lane + 64*j;
        float nv = v[j]*rstd;
        sv[j] = nv * sscale[d];
        rv[j] = nv * rscale[d];
        #pragma unroll
        for (int h=0;h<4;h++){
            pa[h] += sv[j]*w_ada[d*4+h];
            pg[h] += rv[j]*w_gate[d*4+h];
        }
    }
    ushort_t* srow = s + (size_t)tok*DIMM;
    #pragma unroll
    for (int j=0;j<8;j++) srow[lane+64*j] = f2bf(sv[j]);
    if (t >= 63){
        ushort_t* rrow = rc + ((size_t)b*LL + (t-63))*DIMM;
        #pragma unroll
        for (int j=0;j<8;j++) rrow[lane+64*j] = f2bf(rv[j]);
    } else {
        ushort_t* rrow = rc + ((size_t)b*LL + (LL-63+t))*DIMM;
        #pragma unroll
        for (int j=0;j<8;j++) rrow[lane+64*j] = 0;
    }
    #pragma unroll
    for (int h=0;h<4;h++){
        #pragma unroll
        for (int m=1;m<64;m<<=1){
            pa[h] += __shfl_xor(pa[h], m, 64);
            pg[h] += __shfl_xor(pg[h], m, 64);
        }
    }
    if (lane < 4){
        int h = lane;
        lr[((size_t)(b*4+h))*LL + t] = sigmoidf_(pa[h]) * MAX_LR_C;
        if (t >= 63) gate[((size_t)b*LL + (t-63))*4 + h] = sigmoidf_(pg[h]);
        else         gate[((size_t)b*LL + (LL-63+t))*4 + h] = 0.5f;
    }
}

// ---------------------------------------------------------------------------
// Chunk means -> ada_mom/decay. One block per (b,n).
// ---------------------------------------------------------------------------
__global__ __launch_bounds__(256) void k_chunkstats(
    const ushort_t* __restrict__ s, const float* __restrict__ w_mom,
    const float* __restrict__ w_dec, float* __restrict__ ada_mom,
    float* __restrict__ decay)
{
    int b = blockIdx.x >> 6, n = blockIdx.x & 63;
    float pm[4] = {0,0,0,0}, pd[4] = {0,0,0,0};
    #pragma unroll
    for (int rep=0; rep<2; rep++){
        int d = threadIdx.x + rep*256;
        const ushort_t* base = s + ((size_t)b*LL + n*64)*DIMM + d;
        float acc = 0.f;
        for (int c=0;c<64;c++) acc += bf2f(base[(size_t)c*DIMM]);
        float mean = acc * (1.0f/64.0f);
        #pragma unroll
        for (int h=0;h<4;h++){ pm[h] += mean*w_mom[d*4+h]; pd[h] += mean*w_dec[d*4+h]; }
    }
    #pragma unroll
    for (int h=0;h<4;h++){
        #pragma unroll
        for (int m=1;m<64;m<<=1){ pm[h]+=__shfl_xor(pm[h],m,64); pd[h]+=__shfl_xor(pd[h],m,64); }
    }
    __shared__ float lds[4][8];
    int wave = threadIdx.x>>6, lane = threadIdx.x&63;
    if (lane==0){
        #pragma unroll
        for (int h=0;h<4;h++){ lds[wave][h]=pm[h]; lds[wave][4+h]=pd[h]; }
    }
    __syncthreads();
    if (threadIdx.x < 8){
        float tot = lds[0][threadIdx.x]+lds[1][threadIdx.x]+lds[2][threadIdx.x]+lds[3][threadIdx.x];
        int h = threadIdx.x & 3;
        int bh = b*4 + h;
        if (threadIdx.x < 4) ada_mom[bh*64+n] = sigmoidf_(tot);
        else                 decay[bh*64+n]   = sigmoidf_(tot);
    }
}

// ---------------------------------------------------------------------------
// bf16 MFMA GEMM (m97 structure): 128x128 tile, BK=32, 4 waves, 4x4 16x16x32
// tiles per wave, global_load_lds width-16 staging.
// MODE 0 kv:   O1=keys[t][d] hm, O2=keysT[d][t] chunk, O3=vals[t][d] hm
// MODE 4 Q:    O1=q[t][d] head-major
// MODE 5 comb: FO=d_out fp32 with +63 shift
// ---------------------------------------------------------------------------
template<int MODE>
__global__ __launch_bounds__(256) void k_mm(
    const ushort_t* __restrict__ A, const ushort_t* __restrict__ BT,
    ushort_t* __restrict__ O1, ushort_t* __restrict__ O2, ushort_t* __restrict__ O3,
    float* __restrict__ FO, int M, int N, int K)
{
    __shared__ ushort_t As[128*32];
    __shared__ ushort_t Bs[128*32];
    int tid = threadIdx.x;
    int w = tid>>6, l = tid&63;
    int row0 = blockIdx.y*128, col0 = blockIdx.x*128;
    int wm = (w>>1)*64, wn = (w&1)*64;
    int lr16 = l&15, q = l>>4;
    f32x4 acc[4][4] = {};
    int arow = l>>2;          // 0..15
    int akof = (l&3)<<3;      // 0/8/16/24
    const size_t rA0 = (size_t)(row0 + w*16 + arow)*(size_t)K + akof;
    const size_t rA1 = rA0 + (size_t)64*K;
    const size_t rB0 = (size_t)(col0 + w*16 + arow)*(size_t)K + akof;
    const size_t rB1 = rB0 + (size_t)64*K;
    for (int k0=0; k0<K; k0+=32){
        __builtin_amdgcn_global_load_lds((gas1_t)(const void*)(A + rA0 + k0),
                                         (las3_t)(void*)(As + w*512), 16, 0, 0);
        __builtin_amdgcn_global_load_lds((gas1_t)(const void*)(A + rA1 + k0),
                                         (las3_t)(void*)(As + 2048 + w*512), 16, 0, 0);
        __builtin_amdgcn_global_load_lds((gas1_t)(const void*)(BT + rB0 + k0),
                                         (las3_t)(void*)(Bs + w*512), 16, 0, 0);
        __builtin_amdgcn_global_load_lds((gas1_t)(const void*)(BT + rB1 + k0),
                                         (las3_t)(void*)(Bs + 2048 + w*512), 16, 0, 0);
        __syncthreads();
        bf16x8 af[4], bfv[4];
        #pragma unroll
        for (int i=0;i<4;i++){
            af[i]  = *(const bf16x8*)&As[(wm + i*16 + lr16)*32 + q*8];
            bfv[i] = *(const bf16x8*)&Bs[(wn + i*16 + lr16)*32 + q*8];
        }
        #pragma unroll
        for (int i=0;i<4;i++)
            #pragma unroll
            for (int j=0;j<4;j++)
                acc[i][j] = __builtin_amdgcn_mfma_f32_16x16x32_bf16(af[i], bfv[j], acc[i][j], 0,0,0);
        __syncthreads();
    }
    #pragma unroll
    for (int i=0;i<4;i++){
        int trb = row0 + wm + i*16 + q*4;     // 4 consecutive rows
        #pragma unroll
        for (int j=0;j<4;j++){
            int tcol = col0 + wn + j*16 + lr16;
            f32x4 v = acc[i][j];
            if constexpr (MODE==0){
                int bb = trb>>12, l0 = trb&4095;
                int hh = (tcol>>7)&3, dd = tcol&127;
                size_t hm = ((size_t)(bb*4+hh)*LL + l0)*128 + dd;
                ushort_t e0=f2bf(v[0]), e1=f2bf(v[1]), e2=f2bf(v[2]), e3=f2bf(v[3]);
                if (tcol < 512){
                    O1[hm]=e0; O1[hm+128]=e1; O1[hm+256]=e2; O1[hm+384]=e3;
                    int ch = (bb*4+hh)*64 + (l0>>6);
                    ushort4 pk; pk.x=e0; pk.y=e1; pk.z=e2; pk.w=e3;
                    *(ushort4*)&O2[(size_t)ch*8192 + dd*64 + (l0&63)] = pk;
                } else {
                    O3[hm]=e0; O3[hm+128]=e1; O3[hm+256]=e2; O3[hm+384]=e3;
                }
            } else if constexpr (MODE==4){
                int bb = trb>>12, l0 = trb&4095;
                int hh = tcol>>7, dd = tcol&127;
                size_t hm = ((size_t)(bb*4+hh)*LL + l0)*128 + dd;
                O1[hm]=f2bf(v[0]); O1[hm+128]=f2bf(v[1]); O1[hm+256]=f2bf(v[2]); O1[hm+384]=f2bf(v[3]);
            } else { // 5
                int bb = trb>>12;
                #pragma unroll
                for (int r=0;r<4;r++){
                    int t = (trb&4095)+r;
                    if (t < LL-63)
                        FO[((size_t)bb*LL + t + 63)*DIMM + tcol] = v[r];
                }
            }
        }
    }
}

// ---------------------------------------------------------------------------
// Fused per-chunk store pipeline: H=keys@w0 -> silu -> P=siluH@w1 -> dP ->
// g1T -> dH -> g0T. One block per chunk; all intermediates in 64KB LDS.
// LDS reuse: sK keys->siluHT | sV vals->dP->dHT | sH siluH->dPT | sW slices->keysT
// ---------------------------------------------------------------------------
__global__ __launch_bounds__(256,2) void k_fused(
    const ushort_t* __restrict__ keys, const ushort_t* __restrict__ vals,
    const ushort_t* __restrict__ keysT, const ushort_t* __restrict__ w0T,
    const ushort_t* __restrict__ w1T, const ushort_t* __restrict__ w1row,
    const float* __restrict__ lr, ushort_t* __restrict__ G0,
    ushort_t* __restrict__ G1)
{
    __shared__ ushort_t sK[8192];
    __shared__ ushort_t sV[8192];
    __shared__ ushort_t sH[8192];
    __shared__ ushort_t sW[2][4096];
    ushort_t* sWF = &sW[0][0];
    int ch = blockIdx.x;
    int tid = threadIdx.x;
    int w = tid>>6, l = tid&63, lr16 = l&15, q = l>>4;
    const size_t R0 = (size_t)ch*64;

    auto load_slice = [&](const ushort_t* Wg, int s, ushort_t* dst){
        #pragma unroll
        for (int u=0; u<2; u++){
            int flat = u*2048 + tid*8;
            int r_ = flat>>5, c = flat&31;
            int off = (r_<<5) | (((c>>3) ^ (r_&3))<<3);
            *(uint4*)&dst[off] = *(const uint4*)&Wg[r_*128 + s*32 + c];
        }
    };

    // stage keys, vals into swizzled [64][128]
    #pragma unroll
    for (int it=0; it<4; it++){
        int flat = it*2048 + tid*8;
        int t = flat>>7, d = flat&127;
        int off = (t<<7) | ((((d>>3) ^ (t&15))<<3));
        *(uint4*)&sK[off] = *(const uint4*)&keys[(R0<<7) + flat];
        *(uint4*)&sV[off] = *(const uint4*)&vals[(R0<<7) + flat];
    }
    load_slice(w0T, 0, sW[0]);
    __syncthreads();

    // ---- Phase A: HT[i][t] = sum_a w0T[i][a] keys[t][a]  (M=i 128, N=t 64, K=128)
    f32x4 acc[2][4] = {};
    for (int s=0; s<4; s++){
        if (s<3) load_slice(w0T, s+1, sW[(s+1)&1]);
        const ushort_t* Wc = sW[s&1];
        bf16x8 af[2], bv[4];
        #pragma unroll
        for (int mi=0;mi<2;mi++){
            int r_ = w*32 + mi*16 + lr16;
            af[mi] = *(const bf16x8*)&Wc[(r_<<5) | (((q ^ (r_&3))<<3))];
        }
        #pragma unroll
        for (int nj=0;nj<4;nj++){
            int t = nj*16 + lr16;
            bv[nj] = *(const bf16x8*)&sK[(t<<7) | ((((s*4+q) ^ (t&15))<<3))];
        }
        #pragma unroll
        for (int mi=0;mi<2;mi++)
            #pragma unroll
            for (int nj=0;nj<4;nj++)
                acc[mi][nj] = __builtin_amdgcn_mfma_f32_16x16x32_bf16(af[mi], bv[nj], acc[mi][nj], 0,0,0);
        __syncthreads();
    }
    // epilogue: siluH -> sH [t][i], siluHT -> sK [i][t], silu' -> regs
    f32x4 sp[2][4];
    #pragma unroll
    for (int mi=0;mi<2;mi++){
        int i0 = w*32 + mi*16 + q*4;
        #pragma unroll
        for (int nj=0;nj<4;nj++){
            int t = nj*16 + lr16;
            ushort_t e[4];
            #pragma unroll
            for (int r=0;r<4;r++){
                float hv = acc[mi][nj][r];
                float sg = sigmoidf_(hv);
                float si = hv*sg;
                sp[mi][nj][r] = sg*(1.f + hv*(1.f - sg));
                e[r] = f2bf(si);
                sK[sw128x64(i0+r, t)] = e[r];
            }
            ushort4 pk; pk.x=e[0]; pk.y=e[1]; pk.z=e[2]; pk.w=e[3];
            *(ushort4*)&sH[(t<<7) | ((((i0>>3) ^ (t&15))<<3) | (i0&7))] = pk;
        }
    }

    // ---- Phase B: PT[j][t] = sum_i w1T[j][i] siluH[t][i]
    float lrw[4];
    #pragma unroll
    for (int nj=0;nj<4;nj++) lrw[nj] = lr[R0 + nj*16 + lr16];
    f32x4 accb[2][4] = {};
    load_slice(w1T, 0, sW[0]);
    __syncthreads();
    for (int s=0; s<4; s++){
        if (s<3) load_slice(w1T, s+1, sW[(s+1)&1]);
        const ushort_t* Wc = sW[s&1];
        bf16x8 af[2], bv[4];
        #pragma unroll
        for (int mi=0;mi<2;mi++){
            int r_ = w*32 + mi*16 + lr16;
            af[mi] = *(const bf16x8*)&Wc[(r_<<5) | (((q ^ (r_&3))<<3))];
        }
        #pragma unroll
        for (int nj=0;nj<4;nj++){
            int t = nj*16 + lr16;
            bv[nj] = *(const bf16x8*)&sH[(t<<7) | ((((s*4+q) ^ (t&15))<<3))];
        }
        #pragma unroll
        for (int mi=0;mi<2;mi++)
            #pragma unroll
            for (int nj=0;nj<4;nj++)
                accb[mi][nj] = __builtin_amdgcn_mfma_f32_16x16x32_bf16(af[mi], bv[nj], accb[mi][nj], 0,0,0);
        __syncthreads();
    }
    // epilogue: dP = (2/128)*lr*(P - vals); dP -> sV in-place, dPT -> sH
    #pragma unroll
    for (int mi=0;mi<2;mi++){
        int j0 = w*32 + mi*16 + q*4;
        #pragma unroll
        for (int nj=0;nj<4;nj++){
            int t = nj*16 + lr16;
            int voff = (t<<7) | ((((j0>>3) ^ (t&15))<<3) | (j0&7));
            ushort4 vv = *(ushort4*)&sV[voff];
            float vf[4] = {bf2f(vv.x), bf2f(vv.y), bf2f(vv.z), bf2f(vv.w)};
            ushort_t e[4];
            #pragma unroll
            for (int r=0;r<4;r++){
                float dp = 0.015625f * lrw[nj] * (accb[mi][nj][r] - vf[r]);
                e[r] = f2bf(dp);
                sH[sw128x64(j0+r, t)] = e[r];
            }
            ushort4 pk; pk.x=e[0]; pk.y=e[1]; pk.z=e[2]; pk.w=e[3];
            *(ushort4*)&sV[voff] = pk;
        }
    }
    __syncthreads();

    // ---- Phase C: g1T[j][i] = sum_t dPT[j][t] siluHT[i][t]  (K=64)
    load_slice(w1row, 0, sW[0]);   // prefetch D slice 0
    {
        f32x4 accc[2][8] = {};
        #pragma unroll
        for (int k0=0;k0<64;k0+=32){
            bf16x8 af[2], bv[8];
            #pragma unroll
            for (int mi=0;mi<2;mi++){
                int j_ = w*32 + mi*16 + lr16;
                af[mi] = *(const bf16x8*)&sH[(j_<<6) | (((((k0>>3)+q) ^ (j_&7))<<3))];
            }
            #pragma unroll
            for (int nj=0;nj<8;nj++){
                int i_ = nj*16 + lr16;
                bv[nj] = *(const bf16x8*)&sK[(i_<<6) | (((((k0>>3)+q) ^ (i_&7))<<3))];
            }
            #pragma unroll
            for (int mi=0;mi<2;mi++)
                #pragma unroll
                for (int nj=0;nj<8;nj++)
                    accc[mi][nj] = __builtin_amdgcn_mfma_f32_16x16x32_bf16(af[mi], bv[nj], accc[mi][nj], 0,0,0);
        }
        #pragma unroll
        for (int mi=0;mi<2;mi++){
            int j0 = w*32 + mi*16 + q*4;
            #pragma unroll
            for (int nj=0;nj<8;nj++){
                int i_ = nj*16 + lr16;
                #pragma unroll
                for (int r=0;r<4;r++)
                    G1[(size_t)ch*16384 + (size_t)(j0+r)*128 + i_] = f2bf(accc[mi][nj][r]);
            }
        }
    }
    __syncthreads();

    // ---- Phase D: dHT[i][t] = (sum_j w1[i][j] dP[t][j]) * sp[i][t]
    f32x4 accd[2][4] = {};
    for (int s=0; s<4; s++){
        if (s<3) load_slice(w1row, s+1, sW[(s+1)&1]);
        const ushort_t* Wc = sW[s&1];
        bf16x8 af[2], bv[4];
        #pragma unroll
        for (int mi=0;mi<2;mi++){
            int r_ = w*32 + mi*16 + lr16;
            af[mi] = *(const bf16x8*)&Wc[(r_<<5) | (((q ^ (r_&3))<<3))];
        }
        #pragma unroll
        for (int nj=0;nj<4;nj++){
            int t = nj*16 + lr16;
            bv[nj] = *(const bf16x8*)&sV[(t<<7) | ((((s*4+q) ^ (t&15))<<3))];
        }
        #pragma unroll
        for (int mi=0;mi<2;mi++)
            #pragma unroll
            for (int nj=0;nj<4;nj++)
                accd[mi][nj] = __builtin_amdgcn_mfma_f32_16x16x32_bf16(af[mi], bv[nj], accd[mi][nj], 0,0,0);
        __syncthreads();
    }
    // epilogue: dHT -> sV; load keysT -> sW (flat 8192)
    #pragma unroll
    for (int mi=0;mi<2;mi++){
        int i0 = w*32 + mi*16 + q*4;
        #pragma unroll
        for (int nj=0;nj<4;nj++){
            int t = nj*16 + lr16;
            #pragma unroll
            for (int r=0;r<4;r++)
                sV[sw128x64(i0+r, t)] = f2bf(accd[mi][nj][r] * sp[mi][nj][r]);
        }
    }
    #pragma unroll
    for (int it=0; it<4; it++){
        int flat = it*2048 + tid*8;
        int x = flat>>6, t = flat&63;
        int off = (x<<6) | ((((t>>3) ^ (x&7))<<3));
        *(uint4*)&sWF[off] = *(const uint4*)&keysT[(size_t)ch*8192 + flat];
    }
    __syncthreads();

    // ---- Phase E: g0T[i][a] = sum_t dHT[i][t] keysT[a][t]  (K=64)
    {
        f32x4 acce[2][8] = {};
        #pragma unroll
        for (int k0=0;k0<64;k0+=32){
            bf16x8 af[2], bv[8];
            #pragma unroll
            for (int mi=0;mi<2;mi++){
                int i_ = w*32 + mi*16 + lr16;
                af[mi] = *(const bf16x8*)&sV[(i_<<6) | (((((k0>>3)+q) ^ (i_&7))<<3))];
            }
            #pragma unroll
            for (int nj=0;nj<8;nj++){
                int a_ = nj*16 + lr16;
                bv[nj] = *(const bf16x8*)&sWF[(a_<<6) | (((((k0>>3)+q) ^ (a_&7))<<3))];
            }
            #pragma unroll
            for (int mi=0;mi<2;mi++)
                #pragma unroll
                for (int nj=0;nj<8;nj++)
                    acce[mi][nj] = __builtin_amdgcn_mfma_f32_16x16x32_bf16(af[mi], bv[nj], acce[mi][nj], 0,0,0);
        }
        #pragma unroll
        for (int mi=0;mi<2;mi++){
            int i0 = w*32 + mi*16 + q*4;
            #pragma unroll
            for (int nj=0;nj<8;nj++){
                int a_ = nj*16 + lr16;
                #pragma unroll
                for (int r=0;r<4;r++)
                    G0[(size_t)ch*16384 + (size_t)(i0+r)*128 + a_] = f2bf(acce[mi][nj][r]);
            }
        }
    }
}

// ---------------------------------------------------------------------------
// Both linear-recurrence scans in one dispatch (blocks 0..511: g0, 512..: g1).
// ---------------------------------------------------------------------------
__global__ __launch_bounds__(256) void k_scan2(
    const ushort_t* __restrict__ G0, const ushort_t* __restrict__ G1,
    const float* __restrict__ w0T_f, const float* __restrict__ w1T_f,
    const float* __restrict__ am, const float* __restrict__ dec,
    ushort_t* __restrict__ wt0T, ushort_t* __restrict__ wt1T)
{
    int half = blockIdx.x >> 9;
    int gidx = (blockIdx.x & 511)*256 + threadIdx.x;
    const ushort_t* G = half ? G1 : G0;
    const float* winit = half ? w1T_f : w0T_f;
    ushort_t* wt = half ? wt1T : wt0T;
    int bh = gidx >> 14;
    int rem = gidx & 16383;
    float wv = winit[rem];
    float mom = 0.f, upd = 0.f;
    for (int n=0;n<64;n++){
        size_t idx = ((size_t)(bh*64 + n))*16384 + rem;
        float sur = -bf2f(G[idx]);
        float a = am[bh*64+n];
        float d = dec[bh*64+n];
        mom = (n==0) ? sur : a*mom + sur;
        upd = (n==0) ? mom : (1.f - d)*upd + mom;
        wt[idx] = f2bf(wv + upd);
    }
}

// ---------------------------------------------------------------------------
// Retrieve: per chunk, out = silu(Q @ w0t) @ w1t with wt stored transposed,
// then per-row rmsnorm * (gamma+1) * gate.
// ---------------------------------------------------------------------------
__global__ __launch_bounds__(256) void k_retr(
    const ushort_t* __restrict__ Q, const ushort_t* __restrict__ W0t,
    const ushort_t* __restrict__ W1t, const float* __restrict__ gamma,
    const float* __restrict__ gate, ushort_t* __restrict__ out_pre)
{
    int chunk = blockIdx.x;
    int bh = chunk>>6, n = chunk&63, b = bh>>2, h = bh&3;
    __shared__ ushort_t Qs[64*136];
    __shared__ ushort_t Ws[128*136];
    __shared__ ushort_t O1s[64*136];
    int tid = threadIdx.x;
    const ushort_t* Qb = Q + (size_t)chunk*8192;
    #pragma unroll
    for (int it=0; it<4; it++){
        int i = tid*8 + it*2048;
        int row=i>>7, c=i&127;
        *(uint4*)&Qs[row*136+c] = *(const uint4*)&Qb[i];
    }
    const ushort_t* W0b = W0t + (size_t)chunk*16384;
    #pragma unroll
    for (int it=0; it<8; it++){
        int i = tid*8 + it*2048;
        int row=i>>7, c=i&127;
        *(uint4*)&Ws[row*136+c] = *(const uint4*)&W0b[i];
    }
    __syncthreads();
    int w=tid>>6, l=tid&63, lr16=l&15, q=l>>4;
    f32x4 acc[8] = {};
    #pragma unroll
    for (int k0=0;k0<128;k0+=32){
        bf16x8 af = *(const bf16x8*)&Qs[(w*16+lr16)*136 + k0 + q*8];
        #pragma unroll
        for (int j=0;j<8;j++){
            bf16x8 bv = *(const bf16x8*)&Ws[(j*16+lr16)*136 + k0 + q*8];
            acc[j] = __builtin_amdgcn_mfma_f32_16x16x32_bf16(af, bv, acc[j], 0,0,0);
        }
    }
    #pragma unroll
    for (int j=0;j<8;j++){
        #pragma unroll
        for (int r=0;r<4;r++){
            float hv = acc[j][r];
            float sg = sigmoidf_(hv);
            O1s[(w*16+q*4+r)*136 + j*16+lr16] = f2bf(hv*sg);
        }
    }
    __syncthreads();
    const ushort_t* W1b = W1t + (size_t)chunk*16384;
    #pragma unroll
    for (int it=0; it<8; it++){
        int i = tid*8 + it*2048;
        int row=i>>7, c=i&127;
        *(uint4*)&Ws[row*136+c] = *(const uint4*)&W1b[i];
    }
    __syncthreads();
    f32x4 acc2[8] = {};
    #pragma unroll
    for (int k0=0;k0<128;k0+=32){
        bf16x8 af = *(const bf16x8*)&O1s[(w*16+lr16)*136 + k0 + q*8];
        #pragma unroll
        for (int j=0;j<8;j++){
            bf16x8 bv = *(const bf16x8*)&Ws[(j*16+lr16)*136 + k0 + q*8];
            acc2[j] = __builtin_amdgcn_mfma_f32_16x16x32_bf16(af, bv, acc2[j], 0,0,0);
        }
    }
    float ssq[4] = {0,0,0,0};
    #pragma unroll
    for (int j=0;j<8;j++)
        #pragma unroll
        for (int r=0;r<4;r++) ssq[r] += acc2[j][r]*acc2[j][r];
    #pragma unroll
    for (int r=0;r<4;r++){
        ssq[r] += __shfl_xor(ssq[r], 1, 64);
        ssq[r] += __shfl_xor(ssq[r], 2, 64);
        ssq[r] += __shfl_xor(ssq[r], 4, 64);
        ssq[r] += __shfl_xor(ssq[r], 8, 64);
    }
    int tok0 = n*64 + w*16 + q*4;
    #pragma unroll
    for (int r=0;r<4;r++){
        float rstd = rsqrtf(ssq[r]*(1.0f/128.0f) + EPS_C);
        float gv = gate[((size_t)b*LL + tok0 + r)*4 + h];
        #pragma unroll
        for (int j=0;j<8;j++){
            int d = j*16 + lr16;
            float val = acc2[j][r]*rstd*(gamma[h*128+d]+1.0f)*gv;
            out_pre[((size_t)b*LL + tok0 + r)*DIMM + h*128 + d] = f2bf(val);
        }
    }
}

__global__ void k_empty(const float* __restrict__ e, float* __restrict__ out){
    int i = blockIdx.x*256 + threadIdx.x;
    if (i >= BB*63*DIMM) return;
    int b = i / (63*DIMM);
    int r = i % (63*DIMM);
    int t = r / DIMM, d = r % DIMM;
    out[((size_t)b*LL + t)*DIMM + d] = e[d];
}

extern "C" void kernel_launch(void* const* d_in, const int* in_sizes, int n_in,
                              void* d_out, int out_size, void* d_ws, size_t ws_size,
                              hipStream_t stream)
{
    (void)in_sizes; (void)n_in; (void)out_size; (void)ws_size;
    const float* seq    = (const float*)d_in[0];
    const float* sscale = (const float*)d_in[1];
    const float* rscale = (const float*)d_in[2];
    const float* w_q    = (const float*)d_in[3];
    const float* w_kv   = (const float*)d_in[4];
    const float* w_ada  = (const float*)d_in[5];
    const float* w_mom  = (const float*)d_in[6];
    const float* w_dec  = (const float*)d_in[7];
    const float* w0     = (const float*)d_in[8];
    const float* w1     = (const float*)d_in[9];
    const float* gamma  = (const float*)d_in[10];
    const float* w_gate = (const float*)d_in[11];
    const float* w_comb = (const float*)d_in[12];
    const float* empty  = (const float*)d_in[13];
    float* out = (float*)d_out;
    char* wsb = (char*)d_ws;

    ushort_t* bufS  = (ushort_t*)(wsb + 0);          // s
    ushort_t* bufK  = (ushort_t*)(wsb + 8388608);    // keys -> out_pre
    ushort_t* bufV  = (ushort_t*)(wsb + 16777216);   // vals
    ushort_t* bufKT = (ushort_t*)(wsb + 25165824);   // keysT
    ushort_t* bufRC = (ushort_t*)(wsb + 33554432);   // rc (shifted)
    ushort_t* bufQ  = (ushort_t*)(wsb + 41943040);   // q
    ushort_t* G0    = (ushort_t*)(wsb + 50331648);   // 16.8MB
    ushort_t* G1    = (ushort_t*)(wsb + 67108864);   // 16.8MB
    ushort_t* wt0T  = (ushort_t*)(wsb + 83886080);   // 16.8MB
    ushort_t* wt1T  = (ushort_t*)(wsb + 100663296);  // 16.8MB
    ushort_t* w_kvT   = (ushort_t*)(wsb + 117440512);
    ushort_t* w_qT    = (ushort_t*)(wsb + 118489088);
    ushort_t* w_combT = (ushort_t*)(wsb + 119013376);
    ushort_t* w0T_b   = (ushort_t*)(wsb + 119537664);
    ushort_t* w1T_b   = (ushort_t*)(wsb + 119570432);
    ushort_t* w1row_b = (ushort_t*)(wsb + 119603200);
    float* w0T_f = (float*)(wsb + 119635968);
    float* w1T_f = (float*)(wsb + 119701504);
    float* lrbuf = (float*)(wsb + 119767040);
    float* gtbuf = (float*)(wsb + 119898112);
    float* ambuf = (float*)(wsb + 120029184);
    float* dcbuf = (float*)(wsb + 120031232);

    k_convert<<<4288, 256, 0, stream>>>(w_kv, w_q, w_comb, w0, w1,
        w_kvT, w_qT, w_combT, w0T_b, w1T_b, w1row_b, w0T_f, w1T_f);
    k_rmsnorm<<<TOK/4, 256, 0, stream>>>(seq, sscale, rscale, w_ada, w_gate,
        bufS, bufRC, lrbuf, gtbuf);
    k_chunkstats<<<128, 256, 0, stream>>>(bufS, w_mom, w_dec, ambuf, dcbuf);
    // kv: keys(bufK) keysT(bufKT) vals(bufV)
    k_mm<0><<<dim3(8,64), 256, 0, stream>>>(bufS, w_kvT, bufK, bufKT, bufV,
        nullptr, 8192, 1024, 512);
    // fused store pipeline -> g0T(G0), g1T(G1)
    k_fused<<<NCH, 256, 0, stream>>>(bufK, bufV, bufKT, w0T_b, w1T_b, w1row_b,
        lrbuf, G0, G1);
    // both scans -> wt0T / wt1T
    k_scan2<<<1024, 256, 0, stream>>>(G0, G1, w0T_f, w1T_f, ambuf, dcbuf,
        wt0T, wt1T);
    // Q = rc @ w_q -> head-major (bufQ)
    k_mm<4><<<dim3(4,64), 256, 0, stream>>>(bufRC, w_qT, bufQ, nullptr, nullptr,
        nullptr, 8192, 512, 512);
    // retrieve -> out_pre (bufK)
    k_retr<<<NCH, 256, 0, stream>>>(bufQ, wt0T, wt1T, gamma, gtbuf, bufK);
    // combine -> d_out (shifted)
    k_mm<5><<<dim3(4,64), 256, 0, stream>>>(bufK, w_combT, nullptr, nullptr, nullptr,
        out, 8192, 512, 512);
    k_empty<<<252, 256, 0, stream>>>(empty, out);
}